// Round 1
// baseline (303.108 us; speedup 1.0000x reference)
//
#include <hip/hip_runtime.h>
#include <hip/hip_bf16.h>
#include <stdint.h>
#include <stddef.h>

// DecoderStepLayer: B=16, Lq=1, L=2048 (self: 2047 hist + dec row; cross: enc 2048),
// D=1024, H=16, DK=DV=64, DF=4096.
//
// Reordered single-token attention (avoids materializing K/V):
//   qp[b,h,d]  = (1/8) * sum_k wk[h,d,k] * (dec @ wq)[b,h,k]
//   s[b,h,l]   = sum_d histcat[b,l,d] * qp[b,h,d]          (bf16 MFMA, streams hist)
//   p          = softmax_l(s)                               (fp32, written to d_out)
//   ctx[b,h,d] = sum_l p[b,h,l] * histcat[b,l,d]            (bf16 MFMA, streams hist)
//   o[b,h,v]   = sum_d ctx[b,h,d] * wv[h,d,v]
//   x          = LN(o @ wo + bo + resid)
// FFN via the same skinny k-split MFMA GEMM. No atomics anywhere (deterministic).

#define DEV __device__ __forceinline__

typedef __attribute__((ext_vector_type(8))) short bf16x8;
typedef __attribute__((ext_vector_type(4))) float f32x4;

DEV unsigned short f2b(float f){
  union { __hip_bfloat16 h; unsigned short u; } cv;
  cv.h = __float2bfloat16(f);
  return cv.u;
}
DEV float b2f(unsigned short u){
  union { unsigned int i; float f; } cv;
  cv.i = ((unsigned int)u) << 16;
  return cv.f;
}
DEV f32x4 mfma16(bf16x8 a, bf16x8 b, f32x4 c){
  return __builtin_amdgcn_mfma_f32_16x16x32_bf16(a, b, c, 0, 0, 0);
}

// ---------------------------------------------------------------------------
// K1a: Qb[b,h,k] = bf16( scale * sum_d src[b,d] * wq[h,d,k] )   grid 256, blk 256
__global__ __launch_bounds__(256) void k_qproj(const float* __restrict__ src,
    const float* __restrict__ wq, unsigned short* __restrict__ Qb, float scale){
  int bh = blockIdx.x, b = bh >> 4, h = bh & 15;
  int t = threadIdx.x, k = t & 63, q = t >> 6;
  const float* s = src + (size_t)b*1024 + q*256;
  const float* w = wq + (size_t)h*65536 + (size_t)(q*256)*64 + k;
  float a0=0.f,a1=0.f,a2=0.f,a3=0.f;
  for(int d=0; d<256; d+=4){
    a0 += s[d]   * w[(size_t)d*64];
    a1 += s[d+1] * w[(size_t)(d+1)*64];
    a2 += s[d+2] * w[(size_t)(d+2)*64];
    a3 += s[d+3] * w[(size_t)(d+3)*64];
  }
  __shared__ float red[256];
  red[t] = a0+a1+a2+a3;
  __syncthreads();
  if(t < 64){
    float v = red[t] + red[t+64] + red[t+128] + red[t+192];
    Qb[(size_t)bh*64 + t] = f2b(v*scale);
  }
}

// K1b: qpb[b,h,d] = bf16( sum_k wk[h,d,k] * Q[b,h,k] )          grid 256, blk 256
__global__ __launch_bounds__(256) void k_qp(const unsigned short* __restrict__ Qb,
    const float* __restrict__ wk, unsigned short* __restrict__ qpb){
  int bh = blockIdx.x, h = bh & 15;
  __shared__ float Q[64];
  if(threadIdx.x < 64) Q[threadIdx.x] = b2f(Qb[(size_t)bh*64 + threadIdx.x]);
  __syncthreads();
  for(int i=0;i<4;++i){
    int d = threadIdx.x + i*256;
    const float* w = wk + ((size_t)h*1024 + d)*64;
    float acc = 0.f;
    #pragma unroll
    for(int k=0;k<64;k+=4){
      float4 wv = *(const float4*)(w + k);
      acc += wv.x*Q[k] + wv.y*Q[k+1] + wv.z*Q[k+2] + wv.w*Q[k+3];
    }
    qpb[(size_t)bh*1024 + d] = f2b(acc);
  }
}

// K2: scr[b,l,h] = sum_d histcat[b,l,d]*qp[b,h,d]   grid (32,16), blk 256 (4 waves)
// A = hist rows (M=l,K=d) from global (fp32->bf16); B^T = qp[h][d] bf16.
__global__ __launch_bounds__(256) void k_scores(const float* __restrict__ kvsrc,
    const float* __restrict__ decrow, const unsigned short* __restrict__ qpb,
    float* __restrict__ scr, int lsrc){
  int b = blockIdx.y;
  int lane = threadIdx.x & 63;
  int l0 = blockIdx.x*64 + (threadIdx.x >> 6)*16;   // wave's 16-row base
  int hi = lane >> 4;
  int row = l0 + (lane & 15);
  const float* rp = (row < lsrc) ? kvsrc + ((size_t)b*lsrc + row)*1024
                                 : decrow + (size_t)b*1024;
  const float* ap = rp + hi*8;
  const unsigned short* bp = qpb + ((size_t)b*16 + (lane & 15))*1024 + hi*8;
  f32x4 acc = {0.f,0.f,0.f,0.f};
  #pragma unroll 4
  for(int kk=0; kk<1024; kk+=32){
    float4 a0 = *(const float4*)(ap + kk);
    float4 a1 = *(const float4*)(ap + kk + 4);
    bf16x8 af;
    af[0]=(short)f2b(a0.x); af[1]=(short)f2b(a0.y);
    af[2]=(short)f2b(a0.z); af[3]=(short)f2b(a0.w);
    af[4]=(short)f2b(a1.x); af[5]=(short)f2b(a1.y);
    af[6]=(short)f2b(a1.z); af[7]=(short)f2b(a1.w);
    bf16x8 bf_ = *(const bf16x8*)(bp + kk);
    acc = mfma16(af, bf_, acc);
  }
  int h = lane & 15;
  int lbase = l0 + hi*4;
  #pragma unroll
  for(int i=0;i<4;++i)
    scr[((size_t)b*2048 + lbase + i)*16 + h] = acc[i];
}

// K3: softmax over l per (b,h); writes fp32 probs to d_out slice + bf16 to ws.
__global__ __launch_bounds__(256) void k_softmax(const float* __restrict__ scr,
    float* __restrict__ attn_out, unsigned short* __restrict__ pb){
  int b = blockIdx.x >> 4, h = blockIdx.x & 15;
  int t = threadIdx.x;
  __shared__ float red[256];
  const float* s = scr + (size_t)b*2048*16 + h;
  float v[8];
  float m = -1e30f;
  #pragma unroll
  for(int i=0;i<8;++i){ v[i] = s[(size_t)(t + i*256)*16]; m = fmaxf(m, v[i]); }
  red[t] = m; __syncthreads();
  for(int off=128; off>0; off>>=1){ if(t<off) red[t]=fmaxf(red[t],red[t+off]); __syncthreads(); }
  m = red[0]; __syncthreads();
  float sum = 0.f;
  #pragma unroll
  for(int i=0;i<8;++i){ v[i] = __expf(v[i]-m); sum += v[i]; }
  red[t] = sum; __syncthreads();
  for(int off=128; off>0; off>>=1){ if(t<off) red[t]+=red[t+off]; __syncthreads(); }
  float inv = 1.f/red[0];
  size_t base = ((size_t)b*16 + h)*2048;
  #pragma unroll
  for(int i=0;i<8;++i){
    float p = v[i]*inv;
    attn_out[base + t + i*256] = p;
    pb[base + t + i*256] = f2b(p);
  }
}

// K4: ctx partials: part[b,ks,h,d] = sum_{l in slice} p[b,h,l]*histcat[b,l,d]
// grid (dt=16, ks=4, b=16), blk 256. LDS-transposed hist tile, pitch 40 bf16.
__global__ __launch_bounds__(256) void k_ctx(const float* __restrict__ kvsrc,
    const float* __restrict__ decrow, const unsigned short* __restrict__ pb,
    float* __restrict__ part, int lsrc){
  int dt = blockIdx.x, ks = blockIdx.y, b = blockIdx.z;
  int d0 = dt*64, l0 = ks*512;
  __shared__ unsigned short lt[64*40];   // [d 64][l 32 + pad], b128-aligned rows
  int t = threadIdx.x, lane = t & 63, w = t >> 6;
  int l_loc = t >> 3, d_off = (t & 7)*8;
  const unsigned short* ap = pb + ((size_t)b*16 + (lane & 15))*2048 + (lane >> 4)*8;
  f32x4 acc = {0.f,0.f,0.f,0.f};
  for(int c=0; c<16; ++c){
    int lrow = l0 + c*32 + l_loc;
    const float* rp = (lrow < lsrc) ? kvsrc + ((size_t)b*lsrc + lrow)*1024
                                    : decrow + (size_t)b*1024;
    float4 x0 = *(const float4*)(rp + d0 + d_off);
    float4 x1 = *(const float4*)(rp + d0 + d_off + 4);
    __syncthreads();                       // prev iter's LDS reads done
    lt[(d_off+0)*40 + l_loc] = f2b(x0.x);
    lt[(d_off+1)*40 + l_loc] = f2b(x0.y);
    lt[(d_off+2)*40 + l_loc] = f2b(x0.z);
    lt[(d_off+3)*40 + l_loc] = f2b(x0.w);
    lt[(d_off+4)*40 + l_loc] = f2b(x1.x);
    lt[(d_off+5)*40 + l_loc] = f2b(x1.y);
    lt[(d_off+6)*40 + l_loc] = f2b(x1.z);
    lt[(d_off+7)*40 + l_loc] = f2b(x1.w);
    __syncthreads();
    bf16x8 af = *(const bf16x8*)(ap + l0 + c*32);
    bf16x8 bf_ = *(const bf16x8*)&lt[(w*16 + (lane & 15))*40 + (lane >> 4)*8];
    acc = mfma16(af, bf_, acc);
  }
  int col = d0 + w*16 + (lane & 15);
  int hrow = (lane >> 4)*4;
  #pragma unroll
  for(int i=0;i<4;++i)
    part[ (((size_t)b*4 + ks)*16 + hrow + i)*1024 + col ] = acc[i];
}

// K4.5: ctx[b,h,d] = sum_ks part                         grid 1024, blk 256
__global__ __launch_bounds__(256) void k_ctxred(const float* __restrict__ part,
    float* __restrict__ ctx){
  int i = blockIdx.x*256 + threadIdx.x;
  int b = i >> 14, hd = i & 16383;
  size_t base = (size_t)b*65536 + hd;
  ctx[i] = part[base] + part[base+16384] + part[base+32768] + part[base+49152];
}

// K5a: ob[b, h*64+v] = bf16( sum_d ctx[b,h,d]*wv[h,d,v] )  grid 256, blk 256
__global__ __launch_bounds__(256) void k_ov(const float* __restrict__ ctx,
    const float* __restrict__ wv, unsigned short* __restrict__ ob){
  int b = blockIdx.x >> 4, h = blockIdx.x & 15;
  int t = threadIdx.x, v = t & 63, q = t >> 6;
  const float* c = ctx + ((size_t)b*16 + h)*1024 + q*256;
  const float* w = wv + (size_t)h*65536 + (size_t)(q*256)*64 + v;
  float a0=0.f,a1=0.f,a2=0.f,a3=0.f;
  for(int d=0; d<256; d+=4){
    a0 += c[d]   * w[(size_t)d*64];
    a1 += c[d+1] * w[(size_t)(d+1)*64];
    a2 += c[d+2] * w[(size_t)(d+2)*64];
    a3 += c[d+3] * w[(size_t)(d+3)*64];
  }
  __shared__ float red[256];
  red[t] = a0+a1+a2+a3;
  __syncthreads();
  if(t < 64){
    float o = red[t] + red[t+64] + red[t+128] + red[t+192];
    ob[(size_t)b*1024 + h*64 + t] = f2b(o);
  }
}

// Skinny GEMM: part[ks,b,n] = A[16,Kslice] @ W[Kslice,N]   (A bf16, W fp32->bf16)
// grid (N/64, KS), blk 256. LDS-transposed W tile (pitch 40).
__global__ __launch_bounds__(256) void k_skgemm(const float* __restrict__ W,
    const unsigned short* __restrict__ A, float* __restrict__ part,
    int N, int K, int KS){
  int nt = blockIdx.x, ks = blockIdx.y;
  int Ksl = K / KS, k0b = ks * Ksl, n0 = nt*64;
  __shared__ unsigned short lt[64*40];
  int t = threadIdx.x, lane = t & 63, w = t >> 6;
  int k_loc = t >> 3, n_off = (t & 7)*8;
  const unsigned short* ap = A + (size_t)(lane & 15)*K + (lane >> 4)*8;
  f32x4 acc = {0.f,0.f,0.f,0.f};
  for(int c=0; c<Ksl; c+=32){
    const float* wp = W + (size_t)(k0b + c + k_loc)*N + n0 + n_off;
    float4 x0 = *(const float4*)wp;
    float4 x1 = *(const float4*)(wp + 4);
    __syncthreads();
    lt[(n_off+0)*40 + k_loc] = f2b(x0.x);
    lt[(n_off+1)*40 + k_loc] = f2b(x0.y);
    lt[(n_off+2)*40 + k_loc] = f2b(x0.z);
    lt[(n_off+3)*40 + k_loc] = f2b(x0.w);
    lt[(n_off+4)*40 + k_loc] = f2b(x1.x);
    lt[(n_off+5)*40 + k_loc] = f2b(x1.y);
    lt[(n_off+6)*40 + k_loc] = f2b(x1.z);
    lt[(n_off+7)*40 + k_loc] = f2b(x1.w);
    __syncthreads();
    bf16x8 af = *(const bf16x8*)(ap + k0b + c);
    bf16x8 bf_ = *(const bf16x8*)&lt[(w*16 + (lane & 15))*40 + (lane >> 4)*8];
    acc = mfma16(af, bf_, acc);
  }
  int col = n0 + w*16 + (lane & 15);
  int r0 = (lane >> 4)*4;
  #pragma unroll
  for(int i=0;i<4;++i)
    part[ ((size_t)ks*16 + r0 + i)*(size_t)N + col ] = acc[i];
}

// LN( sum_ks parts + bias + resid ) * g + bb  -> xout (fp32) [+ bf16]  grid 16
__global__ __launch_bounds__(256) void k_lnres(const float* __restrict__ parts, int KS,
    const float* __restrict__ bias, const float* __restrict__ resid,
    const float* __restrict__ g, const float* __restrict__ bb,
    float* __restrict__ xout, unsigned short* __restrict__ xb16){
  int b = blockIdx.x, t = threadIdx.x;
  __shared__ float red[256];
  float vals[4];
  float lsum = 0.f;
  for(int i=0;i<4;++i){
    int d = t + i*256;
    float s = bias[d] + resid[(size_t)b*1024 + d];
    for(int k=0;k<KS;++k) s += parts[((size_t)k*16 + b)*1024 + d];
    vals[i] = s; lsum += s;
  }
  red[t] = lsum; __syncthreads();
  for(int off=128; off>0; off>>=1){ if(t<off) red[t]+=red[t+off]; __syncthreads(); }
  float mean = red[0]*(1.f/1024.f); __syncthreads();
  float vsum = 0.f;
  for(int i=0;i<4;++i){ float dd = vals[i]-mean; vsum += dd*dd; }
  red[t] = vsum; __syncthreads();
  for(int off=128; off>0; off>>=1){ if(t<off) red[t]+=red[t+off]; __syncthreads(); }
  float rstd = rsqrtf(red[0]*(1.f/1024.f) + 1e-5f);
  for(int i=0;i<4;++i){
    int d = t + i*256;
    float y = (vals[i]-mean)*rstd*g[d] + bb[d];
    if(xout) xout[(size_t)b*1024 + d] = y;
    if(xb16) xb16[(size_t)b*1024 + d] = f2b(y);
  }
}

// relu( sum_ks fparts + b1 ) -> h1 bf16 [16][4096]          grid 256
__global__ __launch_bounds__(256) void k_relu(const float* __restrict__ parts,
    const float* __restrict__ b1, unsigned short* __restrict__ h1){
  int i = blockIdx.x*256 + threadIdx.x;
  int f = i & 4095, b = i >> 12;
  float s = b1[f];
  for(int k=0;k<4;++k) s += parts[((size_t)k*16 + b)*4096 + f];
  h1[i] = f2b(fmaxf(s, 0.f));
}

// ---------------------------------------------------------------------------
extern "C" void kernel_launch(void* const* d_in, const int* in_sizes, int n_in,
                              void* d_out, int out_size, void* d_ws, size_t ws_size,
                              hipStream_t stream){
  const float* dec    = (const float*)d_in[0];
  const float* hist   = (const float*)d_in[1];
  const float* enc    = (const float*)d_in[2];
  const float* wq_s   = (const float*)d_in[3];
  const float* wk_s   = (const float*)d_in[4];
  const float* wv_s   = (const float*)d_in[5];
  const float* wo_s   = (const float*)d_in[6];
  const float* bo_s   = (const float*)d_in[7];
  const float* ln1_g  = (const float*)d_in[8];
  const float* ln1_b  = (const float*)d_in[9];
  const float* wq_c   = (const float*)d_in[10];
  const float* wk_c   = (const float*)d_in[11];
  const float* wv_c   = (const float*)d_in[12];
  const float* wo_c   = (const float*)d_in[13];
  const float* bo_c   = (const float*)d_in[14];
  const float* ln2_g  = (const float*)d_in[15];
  const float* ln2_b  = (const float*)d_in[16];
  const float* ffn_w1 = (const float*)d_in[17];
  const float* ffn_b1 = (const float*)d_in[18];
  const float* ffn_w2 = (const float*)d_in[19];
  const float* ffn_b2 = (const float*)d_in[20];
  const float* ln3_g  = (const float*)d_in[21];
  const float* ln3_b  = (const float*)d_in[22];

  float* out      = (float*)d_out;              // [16][1024]
  float* slf_out  = out + 16384;                // [16][16][2048]
  float* enc_out  = out + 16384 + 524288;       // [16][16][2048]

  char* w = (char*)d_ws;
  float*          scr   = (float*)(w + 0x000000);          // 2 MB  [16][2048][16]
  unsigned short* pb    = (unsigned short*)(w + 0x200000); // 1 MB  [16][16][2048]
  float*          part  = (float*)(w + 0x300000);          // 4 MB  [16][4][16][1024]
  float*          ctx   = (float*)(w + 0x700000);          // 1 MB  [16][16][1024]
  unsigned short* qpb   = (unsigned short*)(w + 0x800000); // 512K  [16][16][1024]
  unsigned short* Qb    = (unsigned short*)(w + 0x880000); // 32K   [16][16][64]
  unsigned short* ob    = (unsigned short*)(w + 0x890000); // 32K   [16][1024]
  float*          x1    = (float*)(w + 0x8A0000);          // 64K
  float*          x2    = (float*)(w + 0x8B0000);          // 64K
  unsigned short* x2b   = (unsigned short*)(w + 0x8C0000); // 32K
  unsigned short* h1b   = (unsigned short*)(w + 0x8D0000); // 128K  [16][4096]
  float*          gpart = (float*)(w + 0x900000);          // 256K  [4][16][1024]
  float*          fpart = (float*)(w + 0x940000);          // 1 MB  [4][16][4096]
  float*          g2part= (float*)(w + 0xA40000);          // 1 MB  [16][16][1024]

  // ---- self attention ----
  k_qproj  <<<256, 256, 0, stream>>>(dec, wq_s, Qb, 0.125f);
  k_qp     <<<256, 256, 0, stream>>>(Qb, wk_s, qpb);
  k_scores <<<dim3(32,16), 256, 0, stream>>>(hist, dec, qpb, scr, 2047);
  k_softmax<<<256, 256, 0, stream>>>(scr, slf_out, pb);
  k_ctx    <<<dim3(16,4,16), 256, 0, stream>>>(hist, dec, pb, part, 2047);
  k_ctxred <<<1024, 256, 0, stream>>>(part, ctx);
  k_ov     <<<256, 256, 0, stream>>>(ctx, wv_s, ob);
  k_skgemm <<<dim3(16,4), 256, 0, stream>>>(wo_s, ob, gpart, 1024, 1024, 4);
  k_lnres  <<<16, 256, 0, stream>>>(gpart, 4, bo_s, dec, ln1_g, ln1_b, x1, (unsigned short*)nullptr);

  // ---- cross attention ----
  k_qproj  <<<256, 256, 0, stream>>>(x1, wq_c, Qb, 0.125f);
  k_qp     <<<256, 256, 0, stream>>>(Qb, wk_c, qpb);
  k_scores <<<dim3(32,16), 256, 0, stream>>>(enc, dec, qpb, scr, 2048);
  k_softmax<<<256, 256, 0, stream>>>(scr, enc_out, pb);
  k_ctx    <<<dim3(16,4,16), 256, 0, stream>>>(enc, dec, pb, part, 2048);
  k_ctxred <<<1024, 256, 0, stream>>>(part, ctx);
  k_ov     <<<256, 256, 0, stream>>>(ctx, wv_c, ob);
  k_skgemm <<<dim3(16,4), 256, 0, stream>>>(wo_c, ob, gpart, 1024, 1024, 4);
  k_lnres  <<<16, 256, 0, stream>>>(gpart, 4, bo_c, x1, ln2_g, ln2_b, x2, x2b);

  // ---- FFN + final LN ----
  k_skgemm <<<dim3(64,4), 256, 0, stream>>>(ffn_w1, x2b, fpart, 4096, 1024, 4);
  k_relu   <<<256, 256, 0, stream>>>(fpart, ffn_b1, h1b);
  k_skgemm <<<dim3(16,16), 256, 0, stream>>>(ffn_w2, h1b, g2part, 1024, 4096, 16);
  k_lnres  <<<16, 256, 0, stream>>>(g2part, 16, ffn_b2, x2, ln3_g, ln3_b, out, (unsigned short*)nullptr);
}